// Round 1
// baseline (4995.746 us; speedup 1.0000x reference)
//
#include <hip/hip_runtime.h>
#include <math.h>

#define B_ 2
#define L_ 2048
#define DMODEL 2048
#define DINNER 4096
#define DSTATE 16
#define DCONV 4
#define DTRANK 128

__device__ __forceinline__ float sigmoidf_(float x){ return 1.f/(1.f+__expf(-x)); }

// out[m,n] = sum_k A[m,k] * W[n,k]   (A: M x K row-major w/ lda, W: N x K row-major w/ ldw)
// EPI==1: out = softplus(out + bias[n])
template<int BM,int BN,int BK,int TM,int TN,int EPI>
__global__ __launch_bounds__(256)
void gemm_tn(const float* __restrict__ A, int lda,
             const float* __restrict__ W, int ldw,
             float* __restrict__ Cc, int ldc,
             const float* __restrict__ bias,
             int M, int N, int K)
{
    static_assert(BM == BN, "loader assumes BM==BN");
    static_assert(BM*BK == 1024, "one float4 per thread");
    __shared__ float As[BK][BM+4];
    __shared__ float Ws[BK][BN+4];
    const int tid = threadIdx.x;
    constexpr int TCOL = BN/TN;
    const int tx = tid % TCOL;
    const int ty = tid / TCOL;
    const int row0 = blockIdx.y*BM;
    const int col0 = blockIdx.x*BN;

    float acc[TM][TN];
    #pragma unroll
    for(int i=0;i<TM;i++)
        #pragma unroll
        for(int j=0;j<TN;j++) acc[i][j]=0.f;

    constexpr int KV = BK/4;          // float4s per row of the k-tile
    const int am = tid / KV;          // row within tile (0..BM-1)
    const int ak = (tid % KV)*4;      // k offset within tile

    for(int k0=0;k0<K;k0+=BK){
        float4 av = *(const float4*)(A + (size_t)(row0+am)*lda + k0 + ak);
        float4 wv;
        const int wn = col0 + am;
        if (wn < N) wv = *(const float4*)(W + (size_t)wn*ldw + k0 + ak);
        else        wv = make_float4(0.f,0.f,0.f,0.f);

        As[ak+0][am]=av.x; As[ak+1][am]=av.y; As[ak+2][am]=av.z; As[ak+3][am]=av.w;
        Ws[ak+0][am]=wv.x; Ws[ak+1][am]=wv.y; Ws[ak+2][am]=wv.z; Ws[ak+3][am]=wv.w;
        __syncthreads();

        #pragma unroll
        for(int k=0;k<BK;k++){
            float ar[TM], wr[TN];
            #pragma unroll
            for(int i=0;i<TM;i++) ar[i]=As[k][ty*TM+i];
            #pragma unroll
            for(int j=0;j<TN;j++) wr[j]=Ws[k][tx*TN+j];
            #pragma unroll
            for(int i=0;i<TM;i++)
                #pragma unroll
                for(int j=0;j<TN;j++) acc[i][j] = fmaf(ar[i], wr[j], acc[i][j]);
        }
        __syncthreads();
    }

    #pragma unroll
    for(int i=0;i<TM;i++){
        const int m = row0 + ty*TM + i;
        #pragma unroll
        for(int j=0;j<TN;j++){
            const int n = col0 + tx*TN + j;
            if (n < N){
                float v = acc[i][j];
                if (EPI==1){
                    v += bias[n];
                    v = (v > 20.f) ? v : log1pf(expf(v));  // softplus
                }
                Cc[(size_t)m*ldc + n] = v;
            }
        }
    }
}

// depthwise causal conv (k=4) + bias + silu.  x stored [b*L + l, d]
__global__ __launch_bounds__(256)
void conv_silu(const float* __restrict__ xbuf, const float* __restrict__ w,
               const float* __restrict__ bias, float* __restrict__ xconv)
{
    const int gid = blockIdx.x*256 + threadIdx.x;   // over B*L*DINNER
    const int d = gid % DINNER;
    const int t = gid / DINNER;                     // b*L + l
    const int l = t % L_;
    float s = bias[d];
    #pragma unroll
    for(int j=0;j<DCONV;j++){
        const int ll = l - (DCONV-1) + j;
        if (ll >= 0)
            s = fmaf(xbuf[(size_t)(t-(DCONV-1)+j)*DINNER + d], w[d*DCONV+j], s);
    }
    xconv[(size_t)t*DINNER + d] = s * sigmoidf_(s);
}

// selective scan: 16 lanes per (b,d) channel, one state n per lane.
// dty holds dt on input; y (gated) written back in-place.
__global__ __launch_bounds__(256)
void scan_kernel(float* dty,
                 const float* __restrict__ xconv,
                 const float* __restrict__ xdbl,
                 const float* __restrict__ zbuf,
                 const float* __restrict__ A_log,
                 const float* __restrict__ Dvec)
{
    const int tid = threadIdx.x;
    const int grp = blockIdx.x*(256/16) + (tid>>4);  // 0 .. B*DINNER-1
    const int n = tid & 15;
    const int b = grp / DINNER;
    const int d = grp % DINNER;

    const float negA = -expf(A_log[d*DSTATE + n]);
    const float Dv = Dvec[d];
    float h = 0.f;

    const size_t base_td = (size_t)b*L_*DINNER + d;
    const size_t base_bc = (size_t)b*L_*(DTRANK + 2*DSTATE);

    for(int l=0;l<L_;l++){
        const size_t idx = base_td + (size_t)l*DINNER;
        const float dt = dty[idx];
        const float xv = xconv[idx];
        const size_t r = base_bc + (size_t)l*(DTRANK + 2*DSTATE);
        const float Bt = xdbl[r + DTRANK + n];
        const float Ct = xdbl[r + DTRANK + DSTATE + n];

        const float dA = __expf(dt * negA);
        h = fmaf(h, dA, dt*xv*Bt);
        float y = h * Ct;
        y += __shfl_xor(y, 1);
        y += __shfl_xor(y, 2);
        y += __shfl_xor(y, 4);
        y += __shfl_xor(y, 8);
        if (n == 0){
            const float zv = zbuf[idx];
            float out = fmaf(xv, Dv, y);
            out *= zv * sigmoidf_(zv);
            dty[idx] = out;
        }
    }
}

extern "C" void kernel_launch(void* const* d_in, const int* in_sizes, int n_in,
                              void* d_out, int out_size, void* d_ws, size_t ws_size,
                              hipStream_t stream) {
    const float* hs      = (const float*)d_in[0];  // (B,L,DMODEL)
    const float* w_in    = (const float*)d_in[1];  // (2*DINNER, DMODEL)
    const float* w_conv  = (const float*)d_in[2];  // (DINNER,1,DCONV)
    const float* b_conv  = (const float*)d_in[3];  // (DINNER)
    const float* w_xproj = (const float*)d_in[4];  // (160, DINNER)
    const float* w_dt    = (const float*)d_in[5];  // (DINNER, DTRANK)
    const float* b_dt    = (const float*)d_in[6];  // (DINNER)
    const float* w_out   = (const float*)d_in[7];  // (DMODEL, DINNER)
    const float* A_log   = (const float*)d_in[8];  // (DINNER, DSTATE)
    const float* Dvec    = (const float*)d_in[9];  // (DINNER)
    float* out = (float*)d_out;

    float* ws    = (float*)d_ws;
    float* xbuf  = ws;                               // M*DINNER   (x, later dt, later y)
    float* zbuf  = xbuf  + (size_t)4096*DINNER;      // M*DINNER
    float* xconv = zbuf  + (size_t)4096*DINNER;      // M*DINNER
    float* xdbl  = xconv + (size_t)4096*DINNER;      // M*160

    const int M = B_*L_;   // 4096
    dim3 blk(256);

    // in_proj: x half and z half
    gemm_tn<128,128,8,8,8,0><<<dim3(DINNER/128, M/128), blk, 0, stream>>>(
        hs, DMODEL, w_in, DMODEL, xbuf, DINNER, nullptr, M, DINNER, DMODEL);
    gemm_tn<128,128,8,8,8,0><<<dim3(DINNER/128, M/128), blk, 0, stream>>>(
        hs, DMODEL, w_in + (size_t)DINNER*DMODEL, DMODEL, zbuf, DINNER, nullptr, M, DINNER, DMODEL);

    // depthwise conv + silu
    conv_silu<<<dim3((size_t)M*DINNER/256), blk, 0, stream>>>(xbuf, w_conv, b_conv, xconv);

    // x_proj -> x_dbl (M x 160)
    gemm_tn<64,64,16,4,4,0><<<dim3((160+63)/64, M/64), blk, 0, stream>>>(
        xconv, DINNER, w_xproj, DINNER, xdbl, 160, nullptr, M, 160, DINNER);

    // dt_proj + bias + softplus -> dt (into xbuf)
    gemm_tn<128,128,8,8,8,1><<<dim3(DINNER/128, M/128), blk, 0, stream>>>(
        xdbl, 160, w_dt, DTRANK, xbuf, DINNER, b_dt, M, DINNER, DTRANK);

    // selective scan + D skip + silu(z) gating; y overwrites dt in xbuf
    scan_kernel<<<dim3(B_*DINNER/16), blk, 0, stream>>>(
        xbuf, xconv, xdbl, zbuf, A_log, Dvec);

    // out_proj
    gemm_tn<128,128,8,8,8,0><<<dim3(DMODEL/128, M/128), blk, 0, stream>>>(
        xbuf, DINNER, w_out, DINNER, out, DMODEL, nullptr, M, DMODEL, DINNER);
}

// Round 2
// 1454.450 us; speedup vs baseline: 3.4348x; 3.4348x over previous
//
#include <hip/hip_runtime.h>
#include <math.h>

#define B_ 2
#define L_ 2048
#define DMODEL 2048
#define DINNER 4096
#define DSTATE 16
#define DCONV 4
#define DTRANK 128

typedef unsigned short ushort_t;
typedef unsigned int uint_t;
typedef __attribute__((ext_vector_type(8))) short bf16x8;
typedef __attribute__((ext_vector_type(4))) float floatx4;

__device__ __forceinline__ float sigmoidf_(float x){ return 1.f/(1.f+__expf(-x)); }
__device__ __forceinline__ ushort_t f2bf(float f){
    uint_t u = __builtin_bit_cast(uint_t, f);
    return (ushort_t)((u + 0x7FFFu + ((u >> 16) & 1u)) >> 16);
}
__device__ __forceinline__ float bf2f(ushort_t h){
    return __builtin_bit_cast(float, (uint_t)h << 16);
}

#define GLD_LDS16(g, l) __builtin_amdgcn_global_load_lds( \
    (const __attribute__((address_space(1))) void*)(g),   \
    (__attribute__((address_space(3))) void*)(l), 16, 0, 0)

// ---------------------------------------------------------------------------
// bf16 MFMA GEMM: C[M,N] = A[M,K] * W[N,K]^T, 128x128 tile, BK=32, 4 waves.
// AF32=1: A is fp32, converted during staging (reg->LDS). Else bf16 via DMA.
// OUTBF=1: store bf16 (ushort), else fp32.
// M,N multiples of 128 except none here; K multiple of 32.
// ---------------------------------------------------------------------------
template<int AF32, int OUTBF>
__global__ __launch_bounds__(256)
void gemm_mfma(const void* __restrict__ Aptr, int lda,
               const ushort_t* __restrict__ W, int ldw,
               void* __restrict__ Cptr, int ldc, int K)
{
    __shared__ ushort_t lsA[128*32];
    __shared__ ushort_t lsW[128*32];
    const int tid  = threadIdx.x;
    const int row0 = blockIdx.y * 128;
    const int col0 = blockIdx.x * 128;
    const int lane = tid & 63;
    const int wv   = tid >> 6;
    const int wm   = (wv >> 1) * 64;
    const int wn   = (wv & 1) * 64;
    const int lr   = lane & 15;
    const int lq   = lane >> 4;

    floatx4 acc[4][4];
    #pragma unroll
    for(int i=0;i<4;i++)
        #pragma unroll
        for(int j=0;j<4;j++)
            #pragma unroll
            for(int r=0;r<4;r++) acc[i][j][r] = 0.f;

    for(int k0 = 0; k0 < K; k0 += 32){
        // ---- W tile staging: async DMA, 2x16B per thread ----
        #pragma unroll
        for(int it=0; it<2; it++){
            const int slot = it*256 + tid;
            const int row  = slot >> 2;
            const int seg  = slot & 3;
            const ushort_t* g = W + (size_t)(col0 + row)*ldw + k0 + seg*8;
            GLD_LDS16(g, &lsW[slot*8]);
        }
        // ---- A tile staging ----
        if (AF32){
            const float* Af = (const float*)Aptr;
            const int row  = tid >> 1;
            const int half = (tid & 1) * 16;
            const float* s = Af + (size_t)(row0 + row)*lda + k0 + half;
            float4 v0 = *(const float4*)(s + 0);
            float4 v1 = *(const float4*)(s + 4);
            float4 v2 = *(const float4*)(s + 8);
            float4 v3 = *(const float4*)(s + 12);
            union { ushort_t u[8]; uint4 q; } p0, p1;
            p0.u[0]=f2bf(v0.x); p0.u[1]=f2bf(v0.y); p0.u[2]=f2bf(v0.z); p0.u[3]=f2bf(v0.w);
            p0.u[4]=f2bf(v1.x); p0.u[5]=f2bf(v1.y); p0.u[6]=f2bf(v1.z); p0.u[7]=f2bf(v1.w);
            p1.u[0]=f2bf(v2.x); p1.u[1]=f2bf(v2.y); p1.u[2]=f2bf(v2.z); p1.u[3]=f2bf(v2.w);
            p1.u[4]=f2bf(v3.x); p1.u[5]=f2bf(v3.y); p1.u[6]=f2bf(v3.z); p1.u[7]=f2bf(v3.w);
            *(uint4*)&lsA[row*32 + half    ] = p0.q;
            *(uint4*)&lsA[row*32 + half + 8] = p1.q;
        } else {
            #pragma unroll
            for(int it=0; it<2; it++){
                const int slot = it*256 + tid;
                const int row  = slot >> 2;
                const int seg  = slot & 3;
                const ushort_t* g = (const ushort_t*)Aptr + (size_t)(row0 + row)*lda + k0 + seg*8;
                GLD_LDS16(g, &lsA[slot*8]);
            }
        }
        __syncthreads();

        bf16x8 af[4], bw[4];
        #pragma unroll
        for(int i=0;i<4;i++){
            af[i] = *(const bf16x8*)&lsA[(wm + i*16 + lr)*32 + lq*8];
            bw[i] = *(const bf16x8*)&lsW[(wn + i*16 + lr)*32 + lq*8];
        }
        #pragma unroll
        for(int i=0;i<4;i++)
            #pragma unroll
            for(int j=0;j<4;j++)
                acc[i][j] = __builtin_amdgcn_mfma_f32_16x16x32_bf16(af[i], bw[j], acc[i][j], 0, 0, 0);
        __syncthreads();
    }

    #pragma unroll
    for(int i=0;i<4;i++){
        #pragma unroll
        for(int r=0;r<4;r++){
            const int row = row0 + wm + i*16 + lq*4 + r;
            #pragma unroll
            for(int j=0;j<4;j++){
                const int col = col0 + wn + j*16 + lr;
                const float v = acc[i][j][r];
                if (OUTBF) ((ushort_t*)Cptr)[(size_t)row*ldc + col] = f2bf(v);
                else       ((float*)  Cptr)[(size_t)row*ldc + col] = v;
            }
        }
    }
}

// ---------------------------------------------------------------------------
// fp32 SGEMM (small GEMMs): out[m,n] = sum_k A[m,k]*W[n,k]
// EPI==1: softplus(out + bias[n]).  OUTBF==1: store bf16.
// ---------------------------------------------------------------------------
template<int BM,int BN,int BK,int TM,int TN,int EPI,int OUTBF>
__global__ __launch_bounds__(256)
void gemm_tn(const float* __restrict__ A, int lda,
             const float* __restrict__ W, int ldw,
             void* __restrict__ Cc, int ldc,
             const float* __restrict__ bias,
             int M, int N, int K)
{
    static_assert(BM == BN, "loader assumes BM==BN");
    static_assert(BM*BK == 1024, "one float4 per thread");
    __shared__ float As[BK][BM+4];
    __shared__ float Ws[BK][BN+4];
    const int tid = threadIdx.x;
    constexpr int TCOL = BN/TN;
    const int tx = tid % TCOL;
    const int ty = tid / TCOL;
    const int row0 = blockIdx.y*BM;
    const int col0 = blockIdx.x*BN;

    float acc[TM][TN];
    #pragma unroll
    for(int i=0;i<TM;i++)
        #pragma unroll
        for(int j=0;j<TN;j++) acc[i][j]=0.f;

    constexpr int KV = BK/4;
    const int am = tid / KV;
    const int ak = (tid % KV)*4;

    for(int k0=0;k0<K;k0+=BK){
        float4 av = *(const float4*)(A + (size_t)(row0+am)*lda + k0 + ak);
        float4 wv;
        const int wnn = col0 + am;
        if (wnn < N) wv = *(const float4*)(W + (size_t)wnn*ldw + k0 + ak);
        else         wv = make_float4(0.f,0.f,0.f,0.f);

        As[ak+0][am]=av.x; As[ak+1][am]=av.y; As[ak+2][am]=av.z; As[ak+3][am]=av.w;
        Ws[ak+0][am]=wv.x; Ws[ak+1][am]=wv.y; Ws[ak+2][am]=wv.z; Ws[ak+3][am]=wv.w;
        __syncthreads();

        #pragma unroll
        for(int k=0;k<BK;k++){
            float ar[TM], wr[TN];
            #pragma unroll
            for(int i=0;i<TM;i++) ar[i]=As[k][ty*TM+i];
            #pragma unroll
            for(int j=0;j<TN;j++) wr[j]=Ws[k][tx*TN+j];
            #pragma unroll
            for(int i=0;i<TM;i++)
                #pragma unroll
                for(int j=0;j<TN;j++) acc[i][j] = fmaf(ar[i], wr[j], acc[i][j]);
        }
        __syncthreads();
    }

    #pragma unroll
    for(int i=0;i<TM;i++){
        const int m = row0 + ty*TM + i;
        #pragma unroll
        for(int j=0;j<TN;j++){
            const int n = col0 + tx*TN + j;
            if (n < N){
                float v = acc[i][j];
                if (EPI==1){
                    v += bias[n];
                    v = (v > 20.f) ? v : log1pf(expf(v));
                }
                if (OUTBF) ((ushort_t*)Cc)[(size_t)m*ldc + n] = f2bf(v);
                else       ((float*)  Cc)[(size_t)m*ldc + n] = v;
            }
        }
    }
}

// depthwise causal conv (k=4) + bias + silu
__global__ __launch_bounds__(256)
void conv_silu(const float* __restrict__ xbuf, const float* __restrict__ w,
               const float* __restrict__ bias, float* __restrict__ xconv)
{
    const int gid = blockIdx.x*256 + threadIdx.x;
    const int d = gid % DINNER;
    const int t = gid / DINNER;
    const int l = t % L_;
    float s = bias[d];
    #pragma unroll
    for(int j=0;j<DCONV;j++){
        const int ll = l - (DCONV-1) + j;
        if (ll >= 0)
            s = fmaf(xbuf[(size_t)(t-(DCONV-1)+j)*DINNER + d], w[d*DCONV+j], s);
    }
    xconv[(size_t)t*DINNER + d] = s * sigmoidf_(s);
}

// f32 -> bf16 cast, 4 elems/thread
__global__ __launch_bounds__(256)
void cvt_bf16(const float* __restrict__ in, ushort_t* __restrict__ out, int n4)
{
    const int i = blockIdx.x*256 + threadIdx.x;
    if (i < n4){
        float4 v = *(const float4*)(in + (size_t)i*4);
        union { ushort_t u[4]; uint2 q; } p;
        p.u[0]=f2bf(v.x); p.u[1]=f2bf(v.y); p.u[2]=f2bf(v.z); p.u[3]=f2bf(v.w);
        *(uint2*)(out + (size_t)i*4) = p.q;
    }
}

// selective scan, 16 lanes per (b,d), unroll 8 with batched prefetch
__global__ __launch_bounds__(256)
void scan_kernel(const ushort_t* __restrict__ dt_bf,
                 const float* __restrict__ xconv,
                 const float* __restrict__ xdbl,
                 const ushort_t* __restrict__ z_bf,
                 const float* __restrict__ A_log,
                 const float* __restrict__ Dvec,
                 ushort_t* __restrict__ y_bf)
{
    const int tid = threadIdx.x;
    const int grp = blockIdx.x*(256/16) + (tid>>4);
    const int n = tid & 15;
    const int b = grp / DINNER;
    const int d = grp % DINNER;

    const float negA = -expf(A_log[d*DSTATE + n]);
    const float Dv = Dvec[d];
    float h = 0.f;

    const size_t base_td = (size_t)b*L_*DINNER + d;
    const size_t base_bc = (size_t)b*L_*(DTRANK + 2*DSTATE);

    for(int l0=0; l0<L_; l0+=8){
        float dtv[8], xvv[8], Btv[8], Ctv[8], zvv[8];
        #pragma unroll
        for(int u=0;u<8;u++){
            const size_t idx = base_td + (size_t)(l0+u)*DINNER;
            dtv[u] = bf2f(dt_bf[idx]);
            xvv[u] = xconv[idx];
            zvv[u] = bf2f(z_bf[idx]);
            const size_t r = base_bc + (size_t)(l0+u)*(DTRANK + 2*DSTATE);
            Btv[u] = xdbl[r + DTRANK + n];
            Ctv[u] = xdbl[r + DTRANK + DSTATE + n];
        }
        float outs[8];
        #pragma unroll
        for(int u=0;u<8;u++){
            const float dA = __expf(dtv[u] * negA);
            h = fmaf(h, dA, dtv[u]*xvv[u]*Btv[u]);
            float y = h * Ctv[u];
            y += __shfl_xor(y, 1);
            y += __shfl_xor(y, 2);
            y += __shfl_xor(y, 4);
            y += __shfl_xor(y, 8);
            outs[u] = fmaf(xvv[u], Dv, y) * (zvv[u] * sigmoidf_(zvv[u]));
        }
        float sel = outs[0];
        #pragma unroll
        for(int u=1;u<8;u++) if (n == u) sel = outs[u];
        if (n < 8)
            y_bf[base_td + (size_t)(l0+n)*DINNER] = f2bf(sel);
    }
}

extern "C" void kernel_launch(void* const* d_in, const int* in_sizes, int n_in,
                              void* d_out, int out_size, void* d_ws, size_t ws_size,
                              hipStream_t stream) {
    const float* hs      = (const float*)d_in[0];
    const float* w_in    = (const float*)d_in[1];
    const float* w_conv  = (const float*)d_in[2];
    const float* b_conv  = (const float*)d_in[3];
    const float* w_xproj = (const float*)d_in[4];
    const float* w_dt    = (const float*)d_in[5];
    const float* b_dt    = (const float*)d_in[6];
    const float* w_out   = (const float*)d_in[7];
    const float* A_log   = (const float*)d_in[8];
    const float* Dvec    = (const float*)d_in[9];
    float* out = (float*)d_out;

    // workspace layout (peak 187.2 MB, known budget >= 203.9 MB from round 1):
    // [0,64M):        xbuf fp32 (in_proj x)  -> later dt_bf [0,32M) + y_bf [32M,64M)
    // [64M,128M):     xconv fp32             -> later w_out_bf
    // [128M,160M):    z_bf (bf16)
    // [160M,162.5M):  xdbl fp32
    // [162.5M,178.5M):w_in_bf (one half at a time)
    char* base = (char*)d_ws;
    float*    xbuf  = (float*)   (base);
    ushort_t* dt_bf = (ushort_t*)(base);
    ushort_t* y_bf  = (ushort_t*)(base + 33554432);
    float*    xconv = (float*)   (base + 67108864);
    ushort_t* wo_bf = (ushort_t*)(base + 67108864);
    ushort_t* z_bf  = (ushort_t*)(base + 134217728);
    float*    xdbl  = (float*)   (base + 167772160);
    ushort_t* wi_bf = (ushort_t*)(base + 170393600);

    const int M = B_*L_;   // 4096
    dim3 blk(256);

    // in_proj x-half: convert weights, bf16 MFMA GEMM (A fp32 staged-convert)
    cvt_bf16<<<dim3((DINNER*DMODEL/4)/256), blk, 0, stream>>>(w_in, wi_bf, DINNER*DMODEL/4);
    gemm_mfma<1,0><<<dim3(DINNER/128, M/128), blk, 0, stream>>>(
        hs, DMODEL, wi_bf, DMODEL, xbuf, DINNER, DMODEL);

    // in_proj z-half -> bf16 output
    cvt_bf16<<<dim3((DINNER*DMODEL/4)/256), blk, 0, stream>>>(
        w_in + (size_t)DINNER*DMODEL, wi_bf, DINNER*DMODEL/4);
    gemm_mfma<1,1><<<dim3(DINNER/128, M/128), blk, 0, stream>>>(
        hs, DMODEL, wi_bf, DMODEL, z_bf, DINNER, DMODEL);

    // depthwise conv + silu
    conv_silu<<<dim3((size_t)M*DINNER/256), blk, 0, stream>>>(xbuf, w_conv, b_conv, xconv);

    // x_proj (fp32): M x 160
    gemm_tn<64,64,16,4,4,0,0><<<dim3((160+63)/64, M/64), blk, 0, stream>>>(
        xconv, DINNER, w_xproj, DINNER, xdbl, 160, nullptr, M, 160, DINNER);

    // dt_proj + bias + softplus -> dt (bf16)
    gemm_tn<128,128,8,8,8,1,1><<<dim3(DINNER/128, M/128), blk, 0, stream>>>(
        xdbl, 160, w_dt, DTRANK, dt_bf, DINNER, b_dt, M, DINNER, DTRANK);

    // selective scan + D skip + silu(z) gate -> y_bf
    scan_kernel<<<dim3(B_*DINNER/16), blk, 0, stream>>>(
        dt_bf, xconv, xdbl, z_bf, A_log, Dvec, y_bf);

    // out_proj: convert weights (into dead xconv slot), bf16 MFMA GEMM
    cvt_bf16<<<dim3((DMODEL*DINNER/4)/256), blk, 0, stream>>>(w_out, wo_bf, DMODEL*DINNER/4);
    gemm_mfma<0,0><<<dim3(DMODEL/128, M/128), blk, 0, stream>>>(
        y_bf, DINNER, wo_bf, DINNER, out, DMODEL, DINNER);
}